// Round 3
// baseline (194.659 us; speedup 1.0000x reference)
//
#include <hip/hip_runtime.h>
#include <hip/hip_bf16.h>

// FiLM + 2-layer preact resnet, fully fused. N=65536, H=256, C=512.
// GEMMs in bf16 MFMA (16x16x32), fp32 accum. Weights pre-packed into
// MFMA B-fragment order in d_ws by a tiny prep kernel.
// Round 2 (resubmit after infra failure): 32-row blocks, 32KB LDS
// (4 blocks/CU), x staged in LDS bf16, coalesced float4 epilogue via
// LDS transpose.

typedef __attribute__((ext_vector_type(8))) short bf16x8;   // 8 bf16 = 4 VGPR
typedef __attribute__((ext_vector_type(4))) float f32x4;    // MFMA C/D

typedef unsigned short ushort_t;
typedef unsigned int uint_t;

__device__ __forceinline__ ushort_t f2bf(float f) {
  union { float f; uint_t u; } v; v.f = f;
  uint_t u = v.u;
  return (ushort_t)((u + 0x7FFFu + ((u >> 16) & 1u)) >> 16);  // RNE
}
__device__ __forceinline__ float bf2f(ushort_t s) {
  union { uint_t u; float f; } v; v.u = ((uint_t)s) << 16;
  return v.f;
}

// ---------------------------------------------------------------------------
// Pack weights (fp32 row-major [K][Ncols]) into bf16 MFMA-B fragment order:
//   p[((nt*KT + kt)*64 + lane)*8 + j] = W[kt*32 + (lane>>4)*8 + j][nt*16 + (lane&15)]
// ---------------------------------------------------------------------------
__global__ void pack_weights(const float* __restrict__ Wf,
                             const float* __restrict__ W1,
                             const float* __restrict__ W2,
                             ushort_t* __restrict__ p1,
                             ushort_t* __restrict__ pW1,
                             ushort_t* __restrict__ pW2) {
  int u = blockIdx.x * 256 + threadIdx.x;
  if (u < 32768) {
    int lane = u & 63, rest = u >> 6;
    int kt = rest & 15;
    int kb = kt * 32 + (lane >> 4) * 8;
    int col = (rest >> 4) * 16 + (lane & 15);
#pragma unroll
    for (int j = 0; j < 8; ++j)
      p1[(size_t)u * 8 + j] = f2bf(Wf[(size_t)(kb + j) * 512 + col]);
  } else if (u < 40960) {
    int v = u - 32768;
    int lane = v & 63;
    int kt = (v >> 6) & 7;
    int kb = kt * 32 + (lane >> 4) * 8;
    int col = (v >> 9) * 16 + (lane & 15);
#pragma unroll
    for (int j = 0; j < 8; ++j)
      pW1[(size_t)v * 8 + j] = f2bf(W1[(size_t)(kb + j) * 256 + col]);
  } else if (u < 49152) {
    int v = u - 40960;
    int lane = v & 63;
    int kt = (v >> 6) & 7;
    int kb = kt * 32 + (lane >> 4) * 8;
    int col = (v >> 9) * 16 + (lane & 15);
#pragma unroll
    for (int j = 0; j < 8; ++j)
      pW2[(size_t)v * 8 + j] = f2bf(W2[(size_t)(kb + j) * 256 + col]);
  }
}

// ---------------------------------------------------------------------------
// Fused kernel: 1 workgroup = 32 rows, 4 waves; wave w owns output columns
// [w*64, w*64+64). LDS 32KB total:
//   condbuf = lds[0,16K):  cond K-half bf16 [32][256] swz  -> later r1
//   xbuf    = lds[16K,32K): x bf16 [32][256] swz           -> later r2
//   epilogue: whole 32KB = out tile fp32 [32][256] swz
// XOR swizzle: byte ^= (row&15)<<4 (16B-granular, keeps alignment).
// ---------------------------------------------------------------------------
__global__ __launch_bounds__(256, 4)
void film_fused(const float* __restrict__ x, const float* __restrict__ cond,
                const float* __restrict__ b_film, const float* __restrict__ b1,
                const float* __restrict__ b2,
                const ushort_t* __restrict__ p1, const ushort_t* __restrict__ pW1,
                const ushort_t* __restrict__ pW2, float* __restrict__ out) {
  __shared__ __align__(16) char lds[32768];
  char* condbuf = lds;
  char* xbuf = lds + 16384;
  const int r0 = blockIdx.x * 32;
  const int t = threadIdx.x;
  const int w = t >> 6;
  const int l = t & 63;
  const int l15 = l & 15;
  const int lhi = l >> 4;

  // ---- stage: x (full) + cond K-half 0. Issue all loads, then convert.
  {
    float4 ca[4], cb[4], xa[4], xb[4];
    int rows[4], k8s[4];
#pragma unroll
    for (int i = 0; i < 4; ++i) {
      int u = i * 256 + t;
      int row = u >> 5, k8 = u & 31;   // [32 rows][32 units of 8 cols]
      rows[i] = row; k8s[i] = k8;
      const float4* cs = reinterpret_cast<const float4*>(cond + (size_t)(r0 + row) * 512 + k8 * 8);
      ca[i] = cs[0]; cb[i] = cs[1];
      const float4* xs = reinterpret_cast<const float4*>(x + (size_t)(r0 + row) * 256 + k8 * 8);
      xa[i] = xs[0]; xb[i] = xs[1];
    }
#pragma unroll
    for (int i = 0; i < 4; ++i) {
      int byte = rows[i] * 512 + k8s[i] * 16;
      byte ^= ((rows[i] & 15) << 4);
      union { bf16x8 v; ushort_t s[8]; } h;
      h.s[0]=f2bf(ca[i].x); h.s[1]=f2bf(ca[i].y); h.s[2]=f2bf(ca[i].z); h.s[3]=f2bf(ca[i].w);
      h.s[4]=f2bf(cb[i].x); h.s[5]=f2bf(cb[i].y); h.s[6]=f2bf(cb[i].z); h.s[7]=f2bf(cb[i].w);
      *reinterpret_cast<bf16x8*>(condbuf + byte) = h.v;
      union { bf16x8 v; ushort_t s[8]; } g;
      g.s[0]=f2bf(xa[i].x); g.s[1]=f2bf(xa[i].y); g.s[2]=f2bf(xa[i].z); g.s[3]=f2bf(xa[i].w);
      g.s[4]=f2bf(xb[i].x); g.s[5]=f2bf(xb[i].y); g.s[6]=f2bf(xb[i].z); g.s[7]=f2bf(xb[i].w);
      *reinterpret_cast<bf16x8*>(xbuf + byte) = g.v;
    }
  }
  __syncthreads();

  // ---- GEMM1: gb = cond @ W_film (K=512, two K-halves through one buffer).
  // acc[m][tt]: tt 0..3 gamma n-tiles (w*4+tt), tt 4..7 beta n-tiles (16+w*4+..)
  f32x4 acc[2][8];
#pragma unroll
  for (int m = 0; m < 2; ++m)
#pragma unroll
    for (int n = 0; n < 8; ++n) acc[m][n] = (f32x4){0.f, 0.f, 0.f, 0.f};

  for (int half = 0; half < 2; ++half) {
    if (half == 1) {
      __syncthreads();  // everyone done reading K-half 0
      float4 ca[4], cb[4];
      int rows[4], k8s[4];
#pragma unroll
      for (int i = 0; i < 4; ++i) {
        int u = i * 256 + t;
        int row = u >> 5, k8 = u & 31;
        rows[i] = row; k8s[i] = k8;
        const float4* cs = reinterpret_cast<const float4*>(cond + (size_t)(r0 + row) * 512 + 256 + k8 * 8);
        ca[i] = cs[0]; cb[i] = cs[1];
      }
#pragma unroll
      for (int i = 0; i < 4; ++i) {
        int byte = rows[i] * 512 + k8s[i] * 16;
        byte ^= ((rows[i] & 15) << 4);
        union { bf16x8 v; ushort_t s[8]; } h;
        h.s[0]=f2bf(ca[i].x); h.s[1]=f2bf(ca[i].y); h.s[2]=f2bf(ca[i].z); h.s[3]=f2bf(ca[i].w);
        h.s[4]=f2bf(cb[i].x); h.s[5]=f2bf(cb[i].y); h.s[6]=f2bf(cb[i].z); h.s[7]=f2bf(cb[i].w);
        *reinterpret_cast<bf16x8*>(condbuf + byte) = h.v;
      }
      __syncthreads();
    }
#pragma unroll
    for (int kt = 0; kt < 8; ++kt) {
      bf16x8 afr[2];
#pragma unroll
      for (int m = 0; m < 2; ++m) {
        int row = m * 16 + l15;
        int byte = row * 512 + kt * 64 + lhi * 16;
        byte ^= ((row & 15) << 4);
        afr[m] = *reinterpret_cast<const bf16x8*>(condbuf + byte);
      }
      int ktg = half * 8 + kt;
#pragma unroll
      for (int tt = 0; tt < 8; ++tt) {
        int nt = (tt < 4) ? (w * 4 + tt) : (16 + w * 4 + (tt - 4));
        bf16x8 bfr = *reinterpret_cast<const bf16x8*>(p1 + ((size_t)(nt * 16 + ktg) * 64 + l) * 8);
#pragma unroll
        for (int m = 0; m < 2; ++m)
          acc[m][tt] = __builtin_amdgcn_mfma_f32_16x16x32_bf16(afr[m], bfr, acc[m][tt], 0, 0, 0);
      }
    }
  }
  __syncthreads();  // all GEMM1 condbuf reads done

  // ---- FiLM: h = relu(gamma*x + beta) -> bf16 r1 into condbuf.
  float xr[2][4][4];
#pragma unroll
  for (int tt = 0; tt < 4; ++tt) {
    int colg = w * 64 + tt * 16 + l15;
    float bg = b_film[colg];
    float bb = b_film[256 + colg];
#pragma unroll
    for (int m = 0; m < 2; ++m) {
#pragma unroll
      for (int reg = 0; reg < 4; ++reg) {
        int row = m * 16 + lhi * 4 + reg;
        int byte = row * 512 + colg * 2;
        byte ^= ((row & 15) << 4);
        float xv = bf2f(*reinterpret_cast<const ushort_t*>(xbuf + byte));
        xr[m][tt][reg] = xv;
        float g = acc[m][tt][reg] + bg;
        float be = acc[m][4 + tt][reg] + bb;
        float h = fmaxf(g * xv + be, 0.f);
        *reinterpret_cast<ushort_t*>(condbuf + byte) = f2bf(h);
      }
    }
  }
  __syncthreads();  // r1 ready; x reads done (xbuf free for r2)

  // ---- GEMM2: r2 = relu(r1 @ W1 + b1) -> xbuf
  f32x4 acc2[2][4];
#pragma unroll
  for (int m = 0; m < 2; ++m)
#pragma unroll
    for (int n = 0; n < 4; ++n) acc2[m][n] = (f32x4){0.f, 0.f, 0.f, 0.f};

#pragma unroll
  for (int kt = 0; kt < 8; ++kt) {
    bf16x8 afr[2];
#pragma unroll
    for (int m = 0; m < 2; ++m) {
      int row = m * 16 + l15;
      int byte = row * 512 + kt * 64 + lhi * 16;
      byte ^= ((row & 15) << 4);
      afr[m] = *reinterpret_cast<const bf16x8*>(condbuf + byte);
    }
#pragma unroll
    for (int tt = 0; tt < 4; ++tt) {
      int nt = w * 4 + tt;
      bf16x8 bfr = *reinterpret_cast<const bf16x8*>(pW1 + ((size_t)(nt * 8 + kt) * 64 + l) * 8);
#pragma unroll
      for (int m = 0; m < 2; ++m)
        acc2[m][tt] = __builtin_amdgcn_mfma_f32_16x16x32_bf16(afr[m], bfr, acc2[m][tt], 0, 0, 0);
    }
  }
#pragma unroll
  for (int tt = 0; tt < 4; ++tt) {
    int colg = w * 64 + tt * 16 + l15;
    float bias = b1[colg];
#pragma unroll
    for (int m = 0; m < 2; ++m) {
#pragma unroll
      for (int reg = 0; reg < 4; ++reg) {
        int row = m * 16 + lhi * 4 + reg;
        float h = fmaxf(acc2[m][tt][reg] + bias, 0.f);
        int byte = row * 512 + colg * 2;
        byte ^= ((row & 15) << 4);
        *reinterpret_cast<ushort_t*>(xbuf + byte) = f2bf(h);
      }
    }
  }
  __syncthreads();  // r2 ready

  // ---- GEMM3: h2 = r2 @ W2
#pragma unroll
  for (int m = 0; m < 2; ++m)
#pragma unroll
    for (int n = 0; n < 4; ++n) acc2[m][n] = (f32x4){0.f, 0.f, 0.f, 0.f};

#pragma unroll
  for (int kt = 0; kt < 8; ++kt) {
    bf16x8 afr[2];
#pragma unroll
    for (int m = 0; m < 2; ++m) {
      int row = m * 16 + l15;
      int byte = row * 512 + kt * 64 + lhi * 16;
      byte ^= ((row & 15) << 4);
      afr[m] = *reinterpret_cast<const bf16x8*>(xbuf + byte);
    }
#pragma unroll
    for (int tt = 0; tt < 4; ++tt) {
      int nt = w * 4 + tt;
      bf16x8 bfr = *reinterpret_cast<const bf16x8*>(pW2 + ((size_t)(nt * 8 + kt) * 64 + l) * 8);
#pragma unroll
      for (int m = 0; m < 2; ++m)
        acc2[m][tt] = __builtin_amdgcn_mfma_f32_16x16x32_bf16(afr[m], bfr, acc2[m][tt], 0, 0, 0);
    }
  }
  __syncthreads();  // all r2 reads done -> whole LDS reusable

  // ---- epilogue: fp32 out tile [32][256] into whole LDS (swz), then
  // coalesced float4 stores.
#pragma unroll
  for (int tt = 0; tt < 4; ++tt) {
    int colg = w * 64 + tt * 16 + l15;
    float bias = b2[colg];
#pragma unroll
    for (int m = 0; m < 2; ++m) {
#pragma unroll
      for (int reg = 0; reg < 4; ++reg) {
        int row = m * 16 + lhi * 4 + reg;
        float v = acc2[m][tt][reg] + bias + xr[m][tt][reg];
        int byte = row * 1024 + colg * 4;
        byte ^= ((row & 15) << 4);
        *reinterpret_cast<float*>(lds + byte) = v;
      }
    }
  }
  __syncthreads();
#pragma unroll
  for (int i = 0; i < 8; ++i) {
    int u = i * 256 + t;
    int row = u >> 6, c4 = u & 63;   // [32 rows][64 units of 4 cols]
    int byte = row * 1024 + c4 * 16;
    byte ^= ((row & 15) << 4);
    float4 v = *reinterpret_cast<const float4*>(lds + byte);
    *reinterpret_cast<float4*>(out + (size_t)(r0 + row) * 256 + c4 * 4) = v;
  }
}

extern "C" void kernel_launch(void* const* d_in, const int* in_sizes, int n_in,
                              void* d_out, int out_size, void* d_ws, size_t ws_size,
                              hipStream_t stream) {
  const float* x      = (const float*)d_in[0];
  const float* cond   = (const float*)d_in[1];
  const float* W_film = (const float*)d_in[2];
  const float* b_film = (const float*)d_in[3];
  const float* W1     = (const float*)d_in[4];
  const float* b1     = (const float*)d_in[5];
  const float* W2     = (const float*)d_in[6];
  const float* b2     = (const float*)d_in[7];
  float* out = (float*)d_out;

  ushort_t* p1  = (ushort_t*)d_ws;      // 512*512 bf16 = 512KB
  ushort_t* pW1 = p1 + 262144;          // 128KB
  ushort_t* pW2 = pW1 + 65536;          // 128KB

  hipLaunchKernelGGL(pack_weights, dim3(192), dim3(256), 0, stream,
                     W_film, W1, W2, p1, pW1, pW2);
  hipLaunchKernelGGL(film_fused, dim3(65536 / 32), dim3(256), 0, stream,
                     x, cond, b_film, b1, b2, p1, pW1, pW2, out);
}

// Round 4
// 108.015 us; speedup vs baseline: 1.8021x; 1.8021x over previous
//
#include <hip/hip_runtime.h>
#include <hip/hip_bf16.h>

// FiLM + 2-layer preact resnet, fully fused. N=65536, H=256, C=512.
// Round 4: M=64 blocks, software-pipelined B-fragment loads (register
// double-buffer, counted vmcnt), x staged in LDS, nontemporal out stores.

typedef __attribute__((ext_vector_type(8))) short bf16x8;   // 8 bf16 = 4 VGPR
typedef __attribute__((ext_vector_type(4))) float f32x4;    // MFMA C/D

typedef unsigned short ushort_t;
typedef unsigned int uint_t;

__device__ __forceinline__ ushort_t f2bf(float f) {
  union { float f; uint_t u; } v; v.f = f;
  uint_t u = v.u;
  return (ushort_t)((u + 0x7FFFu + ((u >> 16) & 1u)) >> 16);  // RNE
}
__device__ __forceinline__ float bf2f(ushort_t s) {
  union { uint_t u; float f; } v; v.u = ((uint_t)s) << 16;
  return v.f;
}
__device__ __forceinline__ bf16x8 ldfrag(const ushort_t* p) {
  return *reinterpret_cast<const bf16x8*>(p);
}

// ---------------------------------------------------------------------------
// Pack weights (fp32 row-major [K][Ncols]) into bf16 MFMA-B fragment order:
//   p[((nt*KT + kt)*64 + lane)*8 + j] = W[kt*32 + (lane>>4)*8 + j][nt*16 + (lane&15)]
// ---------------------------------------------------------------------------
__global__ void pack_weights(const float* __restrict__ Wf,
                             const float* __restrict__ W1,
                             const float* __restrict__ W2,
                             ushort_t* __restrict__ p1,
                             ushort_t* __restrict__ pW1,
                             ushort_t* __restrict__ pW2) {
  int u = blockIdx.x * 256 + threadIdx.x;
  if (u < 32768) {
    int lane = u & 63, rest = u >> 6;
    int kt = rest & 15;
    int kb = kt * 32 + (lane >> 4) * 8;
    int col = (rest >> 4) * 16 + (lane & 15);
#pragma unroll
    for (int j = 0; j < 8; ++j)
      p1[(size_t)u * 8 + j] = f2bf(Wf[(size_t)(kb + j) * 512 + col]);
  } else if (u < 40960) {
    int v = u - 32768;
    int lane = v & 63;
    int kt = (v >> 6) & 7;
    int kb = kt * 32 + (lane >> 4) * 8;
    int col = (v >> 9) * 16 + (lane & 15);
#pragma unroll
    for (int j = 0; j < 8; ++j)
      pW1[(size_t)v * 8 + j] = f2bf(W1[(size_t)(kb + j) * 256 + col]);
  } else if (u < 49152) {
    int v = u - 40960;
    int lane = v & 63;
    int kt = (v >> 6) & 7;
    int kb = kt * 32 + (lane >> 4) * 8;
    int col = (v >> 9) * 16 + (lane & 15);
#pragma unroll
    for (int j = 0; j < 8; ++j)
      pW2[(size_t)v * 8 + j] = f2bf(W2[(size_t)(kb + j) * 256 + col]);
  }
}

// ---------------------------------------------------------------------------
// 1 workgroup = 64 rows, 4 waves; wave w owns output cols [w*64, w*64+64).
// LDS 64KB:
//   hbuf = lds[0,32K):  cond K-half bf16 [64][256] swz -> r1 -> r2 -> epi fp32
//   xbuf = lds[32K,64K): x bf16 [64][256] swz (alive whole kernel)
// XOR swizzle: byte ^= (row&15)<<4.
// ---------------------------------------------------------------------------
__global__ __launch_bounds__(256, 2)
void film_fused(const float* __restrict__ x, const float* __restrict__ cond,
                const float* __restrict__ b_film, const float* __restrict__ b1,
                const float* __restrict__ b2,
                const ushort_t* __restrict__ p1, const ushort_t* __restrict__ pW1,
                const ushort_t* __restrict__ pW2, float* __restrict__ out) {
  __shared__ __align__(16) char lds[65536];
  char* hbuf = lds;
  char* xbuf = lds + 32768;
  const int r0 = blockIdx.x * 64;
  const int t = threadIdx.x;
  const int w = t >> 6;
  const int l = t & 63;
  const int l15 = l & 15;
  const int lhi = l >> 4;

  // ---- stage: x (full, [64][256]) + cond K-half 0 ([64][256])
#pragma unroll
  for (int it = 0; it < 8; ++it) {
    int u = it * 256 + t;
    int row = u >> 5, k8 = u & 31;          // [64 rows][32 units of 8 cols]
    const float4* cs = reinterpret_cast<const float4*>(cond + (size_t)(r0 + row) * 512 + k8 * 8);
    float4 a = cs[0], b = cs[1];
    const float4* xs = reinterpret_cast<const float4*>(x + (size_t)(r0 + row) * 256 + k8 * 8);
    float4 xa = xs[0], xb = xs[1];
    int byte = row * 512 + k8 * 16;
    byte ^= ((row & 15) << 4);
    union { bf16x8 v; ushort_t s[8]; } hc;
    hc.s[0]=f2bf(a.x); hc.s[1]=f2bf(a.y); hc.s[2]=f2bf(a.z); hc.s[3]=f2bf(a.w);
    hc.s[4]=f2bf(b.x); hc.s[5]=f2bf(b.y); hc.s[6]=f2bf(b.z); hc.s[7]=f2bf(b.w);
    *reinterpret_cast<bf16x8*>(hbuf + byte) = hc.v;
    union { bf16x8 v; ushort_t s[8]; } hx;
    hx.s[0]=f2bf(xa.x); hx.s[1]=f2bf(xa.y); hx.s[2]=f2bf(xa.z); hx.s[3]=f2bf(xa.w);
    hx.s[4]=f2bf(xb.x); hx.s[5]=f2bf(xb.y); hx.s[6]=f2bf(xb.z); hx.s[7]=f2bf(xb.w);
    *reinterpret_cast<bf16x8*>(xbuf + byte) = hx.v;
  }

  // ---- GEMM1 B preload (kt=0) issued before the barrier (independent).
  bf16x8 bb[2][8];
#pragma unroll
  for (int tt = 0; tt < 8; ++tt) {
    int nt = (tt < 4) ? (w * 4 + tt) : (16 + w * 4 + (tt - 4));
    bb[0][tt] = ldfrag(p1 + ((nt * 16 + 0) * 64 + l) * 8);
  }
  __syncthreads();

  // ---- GEMM1: gb = cond @ W_film (K=512, 16 kt), B double-buffered.
  f32x4 acc1[4][8];
#pragma unroll
  for (int m = 0; m < 4; ++m)
#pragma unroll
    for (int n = 0; n < 8; ++n) acc1[m][n] = (f32x4){0.f, 0.f, 0.f, 0.f};

#pragma unroll
  for (int ktg = 0; ktg < 16; ++ktg) {
    if (ktg == 8) {       // restage cond K-half 1 into hbuf
      __syncthreads();
#pragma unroll
      for (int it = 0; it < 8; ++it) {
        int u = it * 256 + t;
        int row = u >> 5, k8 = u & 31;
        const float4* cs = reinterpret_cast<const float4*>(cond + (size_t)(r0 + row) * 512 + 256 + k8 * 8);
        float4 a = cs[0], b = cs[1];
        int byte = row * 512 + k8 * 16;
        byte ^= ((row & 15) << 4);
        union { bf16x8 v; ushort_t s[8]; } hc;
        hc.s[0]=f2bf(a.x); hc.s[1]=f2bf(a.y); hc.s[2]=f2bf(a.z); hc.s[3]=f2bf(a.w);
        hc.s[4]=f2bf(b.x); hc.s[5]=f2bf(b.y); hc.s[6]=f2bf(b.z); hc.s[7]=f2bf(b.w);
        *reinterpret_cast<bf16x8*>(hbuf + byte) = hc.v;
      }
      __syncthreads();
    }
    const int cur = ktg & 1;
    if (ktg < 15) {       // prefetch next kt's B fragments
#pragma unroll
      for (int tt = 0; tt < 8; ++tt) {
        int nt = (tt < 4) ? (w * 4 + tt) : (16 + w * 4 + (tt - 4));
        bb[cur ^ 1][tt] = ldfrag(p1 + ((nt * 16 + (ktg + 1)) * 64 + l) * 8);
      }
    }
    bf16x8 afr[4];
    int ktl = ktg & 7;
#pragma unroll
    for (int m = 0; m < 4; ++m) {
      int row = m * 16 + l15;
      int byte = row * 512 + ktl * 64 + lhi * 16;
      byte ^= ((row & 15) << 4);
      afr[m] = *reinterpret_cast<const bf16x8*>(hbuf + byte);
    }
#pragma unroll
    for (int tt = 0; tt < 8; ++tt)
#pragma unroll
      for (int m = 0; m < 4; ++m)
        acc1[m][tt] = __builtin_amdgcn_mfma_f32_16x16x32_bf16(afr[m], bb[cur][tt], acc1[m][tt], 0, 0, 0);
  }
  __syncthreads();  // all GEMM1 A-reads done; hbuf free for r1

  // ---- FiLM: r1 = relu(gamma*x + beta) -> bf16 into hbuf (x from xbuf)
#pragma unroll
  for (int tt = 0; tt < 4; ++tt) {
    int colg = w * 64 + tt * 16 + l15;
    float bg = b_film[colg];
    float bbv = b_film[256 + colg];
#pragma unroll
    for (int m = 0; m < 4; ++m) {
#pragma unroll
      for (int reg = 0; reg < 4; ++reg) {
        int row = m * 16 + lhi * 4 + reg;
        int byte = row * 512 + colg * 2;
        byte ^= ((row & 15) << 4);
        float xv = bf2f(*reinterpret_cast<const ushort_t*>(xbuf + byte));
        float h = fmaxf((acc1[m][tt][reg] + bg) * xv + (acc1[m][4 + tt][reg] + bbv), 0.f);
        *reinterpret_cast<ushort_t*>(hbuf + byte) = f2bf(h);
      }
    }
  }
  // GEMM2 B preload before the barrier
  bf16x8 bb2[2][4];
#pragma unroll
  for (int tt = 0; tt < 4; ++tt) {
    int nt = w * 4 + tt;
    bb2[0][tt] = ldfrag(pW1 + ((nt * 8 + 0) * 64 + l) * 8);
  }
  __syncthreads();  // r1 ready

  // ---- GEMM2: acc2 = r1 @ W1 (K=256, 8 kt), B double-buffered
  f32x4 acc2[4][4];
#pragma unroll
  for (int m = 0; m < 4; ++m)
#pragma unroll
    for (int n = 0; n < 4; ++n) acc2[m][n] = (f32x4){0.f, 0.f, 0.f, 0.f};

#pragma unroll
  for (int kt = 0; kt < 8; ++kt) {
    const int cur = kt & 1;
    if (kt < 7) {
#pragma unroll
      for (int tt = 0; tt < 4; ++tt) {
        int nt = w * 4 + tt;
        bb2[cur ^ 1][tt] = ldfrag(pW1 + ((nt * 8 + (kt + 1)) * 64 + l) * 8);
      }
    }
    bf16x8 afr[4];
#pragma unroll
    for (int m = 0; m < 4; ++m) {
      int row = m * 16 + l15;
      int byte = row * 512 + kt * 64 + lhi * 16;
      byte ^= ((row & 15) << 4);
      afr[m] = *reinterpret_cast<const bf16x8*>(hbuf + byte);
    }
#pragma unroll
    for (int tt = 0; tt < 4; ++tt)
#pragma unroll
      for (int m = 0; m < 4; ++m)
        acc2[m][tt] = __builtin_amdgcn_mfma_f32_16x16x32_bf16(afr[m], bb2[cur][tt], acc2[m][tt], 0, 0, 0);
  }
  __syncthreads();  // all r1 reads done; hbuf free for r2

  // ---- write r2 = relu(acc2 + b1) -> hbuf
#pragma unroll
  for (int tt = 0; tt < 4; ++tt) {
    int colg = w * 64 + tt * 16 + l15;
    float bias = b1[colg];
#pragma unroll
    for (int m = 0; m < 4; ++m) {
#pragma unroll
      for (int reg = 0; reg < 4; ++reg) {
        int row = m * 16 + lhi * 4 + reg;
        int byte = row * 512 + colg * 2;
        byte ^= ((row & 15) << 4);
        *reinterpret_cast<ushort_t*>(hbuf + byte) = f2bf(fmaxf(acc2[m][tt][reg] + bias, 0.f));
      }
    }
  }
  // GEMM3 B preload before the barrier
  bf16x8 bb3[2][4];
#pragma unroll
  for (int tt = 0; tt < 4; ++tt) {
    int nt = w * 4 + tt;
    bb3[0][tt] = ldfrag(pW2 + ((nt * 8 + 0) * 64 + l) * 8);
  }
  __syncthreads();  // r2 ready

  // ---- GEMM3: acc3 = r2 @ W2 (K=256, 8 kt), B double-buffered
  f32x4 acc3[4][4];
#pragma unroll
  for (int m = 0; m < 4; ++m)
#pragma unroll
    for (int n = 0; n < 4; ++n) acc3[m][n] = (f32x4){0.f, 0.f, 0.f, 0.f};

#pragma unroll
  for (int kt = 0; kt < 8; ++kt) {
    const int cur = kt & 1;
    if (kt < 7) {
#pragma unroll
      for (int tt = 0; tt < 4; ++tt) {
        int nt = w * 4 + tt;
        bb3[cur ^ 1][tt] = ldfrag(pW2 + ((nt * 8 + (kt + 1)) * 64 + l) * 8);
      }
    }
    bf16x8 afr[4];
#pragma unroll
    for (int m = 0; m < 4; ++m) {
      int row = m * 16 + l15;
      int byte = row * 512 + kt * 64 + lhi * 16;
      byte ^= ((row & 15) << 4);
      afr[m] = *reinterpret_cast<const bf16x8*>(hbuf + byte);
    }
#pragma unroll
    for (int tt = 0; tt < 4; ++tt)
#pragma unroll
      for (int m = 0; m < 4; ++m)
        acc3[m][tt] = __builtin_amdgcn_mfma_f32_16x16x32_bf16(afr[m], bb3[cur][tt], acc3[m][tt], 0, 0, 0);
  }
  __syncthreads();  // all r2 reads done; hbuf free for epilogue

  // ---- epilogue: two 32-row halves. fp32 tile in hbuf, residual from xbuf,
  // coalesced nontemporal float4 stores.
  float b2v[4];
#pragma unroll
  for (int tt = 0; tt < 4; ++tt) b2v[tt] = b2[w * 64 + tt * 16 + l15];

#pragma unroll
  for (int h = 0; h < 2; ++h) {
#pragma unroll
    for (int tt = 0; tt < 4; ++tt) {
      int colg = w * 64 + tt * 16 + l15;
#pragma unroll
      for (int mm = 0; mm < 2; ++mm) {
        int m = h * 2 + mm;
#pragma unroll
        for (int reg = 0; reg < 4; ++reg) {
          int r = mm * 16 + lhi * 4 + reg;
          int byte = r * 1024 + colg * 4;
          byte ^= ((r & 15) << 4);
          *reinterpret_cast<float*>(hbuf + byte) = acc3[m][tt][reg] + b2v[tt];
        }
      }
    }
    __syncthreads();
#pragma unroll
    for (int i = 0; i < 8; ++i) {
      int u = i * 256 + t;
      int r = u >> 6, c4 = u & 63;       // [32 rows][64 units of 4 cols]
      int byte = r * 1024 + c4 * 16;
      byte ^= ((r & 15) << 4);
      f32x4 v = *reinterpret_cast<const f32x4*>(hbuf + byte);
      int grow = h * 32 + r;
      int xbyte = grow * 512 + c4 * 8;
      xbyte ^= ((grow & 15) << 4);
      const ushort_t* xp = reinterpret_cast<const ushort_t*>(xbuf + xbyte);
      v.x += bf2f(xp[0]); v.y += bf2f(xp[1]); v.z += bf2f(xp[2]); v.w += bf2f(xp[3]);
      f32x4* op = reinterpret_cast<f32x4*>(out + (size_t)(r0 + grow) * 256 + c4 * 4);
      __builtin_nontemporal_store(v, op);
    }
    if (h == 0) __syncthreads();  // before half 1 overwrites hbuf
  }
}

extern "C" void kernel_launch(void* const* d_in, const int* in_sizes, int n_in,
                              void* d_out, int out_size, void* d_ws, size_t ws_size,
                              hipStream_t stream) {
  const float* x      = (const float*)d_in[0];
  const float* cond   = (const float*)d_in[1];
  const float* W_film = (const float*)d_in[2];
  const float* b_film = (const float*)d_in[3];
  const float* W1     = (const float*)d_in[4];
  const float* b1     = (const float*)d_in[5];
  const float* W2     = (const float*)d_in[6];
  const float* b2     = (const float*)d_in[7];
  float* out = (float*)d_out;

  ushort_t* p1  = (ushort_t*)d_ws;      // 512KB
  ushort_t* pW1 = p1 + 262144;          // 128KB
  ushort_t* pW2 = pW1 + 65536;          // 128KB

  hipLaunchKernelGGL(pack_weights, dim3(192), dim3(256), 0, stream,
                     W_film, W1, W2, p1, pW1, pW2);
  hipLaunchKernelGGL(film_fused, dim3(65536 / 64), dim3(256), 0, stream,
                     x, cond, b_film, b1, b2, p1, pW1, pW2, out);
}